// Round 15
// baseline (19462.653 us; speedup 1.0000x reference)
//
#include <hip/hip_runtime.h>
#include <hip/hip_bf16.h>
#include <math.h>

#define NCB 8
#define CBS 1024
#define HID 512
#define NB 8
#define TLAT 4096
#define DELTA 6.0e-5f

__global__ void rf_sentinel(float* out, float v)
{
    out[threadIdx.x] = v;
}

// ---------------- encoder conv: stride 2, pad 7, K=15, ELU — f64 interior, f32 storage ----
// co-blocking 8; per-output FMA chain (ci outer, k inner) bit-identical to r11/r14.
template<int CIN, int COUT, int LIN>
__global__ __launch_bounds__(256)
void rf_enc(const float* __restrict__ x, const float* __restrict__ w,
            const float* __restrict__ bias, float* __restrict__ y)
{
    constexpr int LOUT = LIN / 2;
    __shared__ float xs[2][520];
    const int tid = threadIdx.x;
    const int t0  = blockIdx.x * 512;
    const int co0 = blockIdx.y * 8;
    const int b   = blockIdx.z;
    const float* xb = x + (size_t)b * CIN * LIN;
    const int base = 2 * t0 - 8;

    double acc[8][2];
#pragma unroll
    for (int c = 0; c < 8; ++c) acc[c][0] = acc[c][1] = (double)bias[co0 + c];

    for (int ci = 0; ci < CIN; ++ci) {
        const float* xc = xb + (size_t)ci * LIN;
        __syncthreads();
        for (int idx = tid; idx < 1040; idx += 256) {
            const int xi = base + idx;
            xs[idx & 1][idx >> 1] = ((unsigned)xi < (unsigned)LIN) ? xc[xi] : 0.f;
        }
        __syncthreads();
        const float* wc = w + ((size_t)co0 * CIN + ci) * 15;
#pragma unroll
        for (int k = 0; k < 15; ++k) {
            const int p  = (k + 1) & 1;
            const int jb = (k + 1) >> 1;
            const double x0 = (double)xs[p][tid + jb];
            const double x1 = (double)xs[p][tid + 256 + jb];
#pragma unroll
            for (int c = 0; c < 8; ++c) {
                const double wv = (double)wc[c * CIN * 15 + k];
                acc[c][0] = fma(wv, x0, acc[c][0]);
                acc[c][1] = fma(wv, x1, acc[c][1]);
            }
        }
    }
#pragma unroll
    for (int c = 0; c < 8; ++c) {
        float* yp = y + ((size_t)b * COUT + co0 + c) * LOUT;
        const double a0 = acc[c][0], a1 = acc[c][1];
        yp[t0 + tid]       = (float)(a0 > 0.0 ? a0 : expm1(a0));
        yp[t0 + tid + 256] = (float)(a1 > 0.0 ? a1 : expm1(a1));
    }
}

// ---------------- tiled transpose: in[b][RIN][CIN_] -> out[b][CIN_][RIN] ----------------
template<int RIN, int CIN_>
__global__ __launch_bounds__(256)
void rf_tr(const float* __restrict__ in, float* __restrict__ out)
{
    __shared__ float tile[32][33];
    const int c0 = blockIdx.x * 32, r0 = blockIdx.y * 32, b = blockIdx.z;
    const int lx = threadIdx.x & 31, ly = threadIdx.x >> 5;
    const float* ib = in + (size_t)b * RIN * CIN_;
    float* ob = out + (size_t)b * RIN * CIN_;
#pragma unroll
    for (int m = 0; m < 4; ++m)
        tile[ly + m * 8][lx] = ib[(size_t)(r0 + ly + m * 8) * CIN_ + c0 + lx];
    __syncthreads();
#pragma unroll
    for (int m = 0; m < 4; ++m)
        ob[(size_t)(c0 + ly + m * 8) * RIN + r0 + lx] = tile[lx][ly + m * 8];
}

// ---------------- decoder ConvTranspose1d (f32) — per-output chain verbatim r11 ----------
template<int CIN, int COUT, int LIN, int CO_PER, int ACT>   // ACT 0=ELU, 1=tanh
__global__ __launch_bounds__(256)
void rf_dec(const float* __restrict__ x, const float* __restrict__ w,
            const float* __restrict__ bias, float* __restrict__ y)
{
    constexpr int LOUT = LIN * 2;
    const int u   = blockIdx.x * 256 + threadIdx.x;
    const int co0 = blockIdx.y * CO_PER;
    const int b   = blockIdx.z;

    float acc[CO_PER][2];
#pragma unroll
    for (int c = 0; c < CO_PER; ++c) acc[c][0] = acc[c][1] = bias[co0 + c];

    const float* xb = x + (size_t)b * CIN * LIN;
    for (int ci = 0; ci < CIN; ++ci) {
        const float* xc = xb + (size_t)ci * LIN;
        const float* wc = w + ((size_t)ci * COUT + co0) * 15;
#pragma unroll
        for (int dj = 0; dj < 8; ++dj) {
            const int j = u - 3 + dj;
            const float xv = ((unsigned)j < (unsigned)LIN) ? xc[j] : 0.f;
            const int ke = 13 - 2 * dj;
            const int ko = 14 - 2 * dj;
#pragma unroll
            for (int c = 0; c < CO_PER; ++c) {
                if (ke >= 0) acc[c][0] = fmaf(xv, wc[c * 15 + ke], acc[c][0]);
                acc[c][1] = fmaf(xv, wc[c * 15 + ko], acc[c][1]);
            }
        }
    }
#pragma unroll
    for (int c = 0; c < CO_PER; ++c) {
        float* yp = y + ((size_t)b * COUT + co0 + c) * LOUT + 2 * (size_t)u;
        if (ACT == 0) {
            yp[0] = acc[c][0] > 0.f ? acc[c][0] : expm1f(acc[c][0]);
            yp[1] = acc[c][1] > 0.f ? acc[c][1] : expm1f(acc[c][1]);
        } else {
            yp[0] = tanhf(acc[c][0]);
            yp[1] = tanhf(acc[c][1]);
        }
    }
}

// ---------------- prep: N32[c] = fl32( sum_f64 fl32(c_d^2) ) + zero loss ----------------
__global__ __launch_bounds__(64)
void rf_prep(const float* __restrict__ cb, float* __restrict__ cnormF,
             float* __restrict__ lossp)
{
    __shared__ double red[64];
    const int rrow = blockIdx.x;
    const float* src = cb + (size_t)rrow * HID;
    const int lane = threadIdx.x;
    double s = 0.0;
#pragma unroll
    for (int m = 0; m < 8; ++m) {
        const float v = src[lane * 8 + m];
        s += (double)__fmul_rn(v, v);
    }
    red[lane] = s;
    __syncthreads();
    if (lane == 0) {
        double tot = 0.0;
        for (int i = 0; i < 64; ++i) tot += red[i];
        cnormF[rrow] = (float)tot;
        if (rrow == 0) lossp[0] = 0.f;
    }
}

// ---------------- Z pre-pass (r11 realization): 4 parts of 128 sequential d ----------------
__global__ __launch_bounds__(256)
void rf_z(const float* __restrict__ R, float* __restrict__ Zrow)
{
    __shared__ double zp[64][4];
    const int tid = threadIdx.x;
    const int gr0 = blockIdx.x * 64;
    const int row = tid & 63, p = tid >> 6;
    const float* Rr = R + (size_t)(gr0 + row) * HID + p * 128;
    double s = 0.0;
    for (int i = 0; i < 128; ++i) {
        const float v = Rr[i];
        s += (double)__fmul_rn(v, v);
    }
    zp[row][p] = s;
    __syncthreads();
    if (tid < 64)
        Zrow[gr0 + tid] = (float)(((zp[tid][0] + zp[tid][1]) + zp[tid][2]) + zp[tid][3]);
}

// ---------------- f32 prefilter: per-row tile-16 minima (verbatim r14) ----------------
__global__ __launch_bounds__(256)
void rf_pref(const float* __restrict__ cb, const float* __restrict__ cnormF,
             const float* __restrict__ R, float* __restrict__ tileMin)
{
    __shared__ __align__(16) float Rt[32][64];
    __shared__ __align__(16) float Ct[32][128];
    const int tid = threadIdx.x;
    const int gr0 = blockIdx.x * 64;
    const int cb0 = blockIdx.y * 128;
    const float* Rbase = R + (size_t)gr0 * HID;
    const int ir = tid >> 4, jc = tid & 15;

    float acc[4][8];
#pragma unroll
    for (int r = 0; r < 4; ++r)
#pragma unroll
        for (int c = 0; c < 8; ++c) acc[r][c] = 0.f;

    for (int kc = 0; kc < 16; ++kc) {
        const int k0 = kc * 32;
        __syncthreads();
#pragma unroll
        for (int rep = 0; rep < 2; ++rep) {
            const int row  = (tid >> 3) + 32 * rep;
            const int koff = (tid & 7) * 4;
            const float4 v = *(const float4*)(Rbase + (size_t)row * HID + k0 + koff);
            Rt[koff + 0][row] = v.x; Rt[koff + 1][row] = v.y;
            Rt[koff + 2][row] = v.z; Rt[koff + 3][row] = v.w;
        }
        {
            const int cc = tid >> 1, h = (tid & 1) * 16;
            const float* s = cb + (size_t)(cb0 + cc) * HID + k0 + h;
            const float4 v0 = *(const float4*)s;
            const float4 v1 = *(const float4*)(s + 4);
            const float4 v2 = *(const float4*)(s + 8);
            const float4 v3 = *(const float4*)(s + 12);
            Ct[h + 0][cc] = v0.x; Ct[h + 1][cc] = v0.y; Ct[h + 2][cc] = v0.z; Ct[h + 3][cc] = v0.w;
            Ct[h + 4][cc] = v1.x; Ct[h + 5][cc] = v1.y; Ct[h + 6][cc] = v1.z; Ct[h + 7][cc] = v1.w;
            Ct[h + 8][cc] = v2.x; Ct[h + 9][cc] = v2.y; Ct[h +10][cc] = v2.z; Ct[h +11][cc] = v2.w;
            Ct[h +12][cc] = v3.x; Ct[h +13][cc] = v3.y; Ct[h +14][cc] = v3.z; Ct[h +15][cc] = v3.w;
        }
        __syncthreads();

#pragma unroll
        for (int kk = 0; kk < 32; ++kk) {
            const float4 rv = *(const float4*)&Rt[kk][ir * 4];
            const float4 c0v = *(const float4*)&Ct[kk][jc * 8];
            const float4 c1v = *(const float4*)&Ct[kk][jc * 8 + 4];
            const float rr[4] = {rv.x, rv.y, rv.z, rv.w};
            const float cc8[8] = {c0v.x, c0v.y, c0v.z, c0v.w, c1v.x, c1v.y, c1v.z, c1v.w};
#pragma unroll
            for (int r = 0; r < 4; ++r)
#pragma unroll
                for (int c = 0; c < 8; ++c)
                    acc[r][c] = fmaf(rr[r], cc8[c], acc[r][c]);
        }
    }

#pragma unroll
    for (int r = 0; r < 4; ++r) {
        float m = 3.0e38f;
#pragma unroll
        for (int c = 0; c < 8; ++c) {
            const int ci = cb0 + jc * 8 + c;
            const float s = fmaf(-2.f, acc[r][c], cnormF[ci]);
            m = fminf(m, s);
        }
        const float o = __shfl_xor(m, 1, 64);
        m = fminf(m, o);
        if ((jc & 1) == 0)
            tileMin[(size_t)(gr0 + ir * 4 + r) * 64 + (cb0 >> 4) + (jc >> 1)] = m;
    }
}

// ---------------- exact rescore — wave-parallel: 16 rows x 16 codes per block -------------
// Per (row,code): full-512 d-ascending f64 FMA chain (realization identical to r11/r14).
__global__ __launch_bounds__(256)
void rf_fin(const float* __restrict__ cb, const float* __restrict__ cnormF,
            const float* __restrict__ R, const float* __restrict__ Zrow,
            const float* __restrict__ tileMin, unsigned short* __restrict__ codesOut)
{
    __shared__ float tmS[16][64];
    __shared__ unsigned char tlistS[16][16];
    __shared__ int tcntS[16];

    const int tid = threadIdx.x;
    const int gr0 = blockIdx.x * 16;

    for (int e = tid; e < 16 * 64; e += 256)
        tmS[e >> 6][e & 63] = tileMin[(size_t)(gr0 + (e >> 6)) * 64 + (e & 63)];
    __syncthreads();
    if (tid < 16) {
        float m = 3.0e38f;
        for (int t = 0; t < 64; ++t) m = fminf(m, tmS[tid][t]);
        int cnt = 0;
        const float thr_ = m + DELTA;
        for (int t = 0; t < 64; ++t)
            if (tmS[tid][t] <= thr_) { if (cnt < 16) tlistS[tid][cnt] = (unsigned char)t; ++cnt; }
        tcntS[tid] = (cnt > 16) ? 64 : cnt;
    }
    __syncthreads();

    const int wave = tid >> 6;
    const int lane = tid & 63;
    const int rloc = wave * 4 + (lane >> 4);     // block-local row 0..15
    const int cg   = lane & 15;                  // code within tile
    const int grow = gr0 + rloc;
    const float* Rr = R + (size_t)grow * HID;
    const float Zr = Zrow[grow];
    const int myCnt = tcntS[rloc];

    int maxc = myCnt;                            // max over the wave's 4 rows
    maxc = max(maxc, __shfl_xor(maxc, 16, 64));
    maxc = max(maxc, __shfl_xor(maxc, 32, 64));

    float bestS = 3.0e38f; int bestC = 0x7fffffff;
    for (int li = 0; li < maxc; ++li) {
        if (li < myCnt) {
            const int tt = (myCnt <= 16) ? (int)tlistS[rloc][li] : li;
            const int ci = tt * 16 + cg;
            const float* cp = cb + (size_t)ci * HID;
            double a = 0.0;
            for (int d = 0; d < 512; ++d)
                a = fma((double)Rr[d], (double)cp[d], a);
            const float M32 = (float)a;
            const float s = __fadd_rn(__fsub_rn(Zr, __fadd_rn(M32, M32)), cnormF[ci]);
            if (s < bestS || (s == bestS && ci < bestC)) { bestS = s; bestC = ci; }
        }
    }
    // argmin across the 16 cg lanes of this row group (tie -> lower index)
#pragma unroll
    for (int off = 8; off; off >>= 1) {
        const float ov = __shfl_xor(bestS, off, 16);
        const int   oc = __shfl_xor(bestC, off, 16);
        if (ov < bestS || (ov == bestS && oc < bestC)) { bestS = ov; bestC = oc; }
    }
    if (cg == 0) codesOut[grow] = (unsigned short)bestC;
}

// ---------------- ST update + loss — coalesced (verbatim r14) ----------------
__global__ __launch_bounds__(256)
void rf_comb(const float* __restrict__ cb, const unsigned short* __restrict__ codesIn,
             float* __restrict__ R, float* __restrict__ Q,
             float* __restrict__ loss_acc, int stage)
{
    __shared__ int codes_l[64];
    const int tid = threadIdx.x;
    const int gr0 = blockIdx.x * 64;
    float* Rb = R + (size_t)gr0 * HID;
    float* Qb = Q + (size_t)gr0 * HID;

    if (tid < 64) codes_l[tid] = (int)codesIn[gr0 + tid];
    __syncthreads();

    float ls = 0.f;
    for (int e = tid; e < 64 * HID; e += 256) {
        const int row = e >> 9;
        const int c = codes_l[row];
        const float rr = Rb[e];
        const float q = cb[(size_t)c * HID + (e & 511)];
        const float diff  = __fsub_rn(q, rr);
        const float zqst  = __fadd_rn(rr, diff);
        ls = fmaf(diff, diff, ls);
        Rb[e] = __fsub_rn(rr, zqst);
        if (stage == 0) Qb[e] = zqst; else Qb[e] = __fadd_rn(Qb[e], zqst);
    }
#pragma unroll
    for (int off = 32; off; off >>= 1) ls += __shfl_down(ls, off, 64);
    if ((tid & 63) == 0) atomicAdd(loss_acc, ls);
}

// ---------------- single writer of d_out (f32), last dispatch ----------------
__global__ __launch_bounds__(256)
void rf_emit(const float* __restrict__ reconF, const unsigned short* __restrict__ codes_ws,
             const float* __restrict__ loss_acc, float* __restrict__ out)
{
    const int j = blockIdx.x * 256 + threadIdx.x;
    if (j >= 524288 + 1 + NCB * 32768) return;
    if (j < 524288)       out[j] = reconF[j];
    else if (j == 524288) out[j] = loss_acc[0] * 1.25f * (1.0f / 16777216.0f);
    else                  out[j] = (float)codes_ws[j - 524289];
}

extern "C" void kernel_launch(void* const* d_in, const int* in_sizes, int n_in,
                              void* d_out, int out_size, void* d_ws, size_t ws_size,
                              hipStream_t stream)
{
    float* out = (float*)d_out;

    if (n_in != 18)                                   { rf_sentinel<<<1, 256, 0, stream>>>(out, 1111.0f); return; }
    if (in_sizes[0] != 8 * 65536 || in_sizes[9] != NCB * CBS * HID ||
        in_sizes[1] != 64 * 15 || in_sizes[10] != 512 * 256 * 15)
                                                      { rf_sentinel<<<1, 256, 0, stream>>>(out, 3333.0f); return; }
    if (out_size != 524288 + 1 + NCB * 32768)         { rf_sentinel<<<1, 256, 0, stream>>>(out, 5555.0f); return; }
    if (ws_size < (size_t)137 * 1024 * 1024)          { rf_sentinel<<<1, 256, 0, stream>>>(out, 7777.0f); return; }

    const float* audio = (const float*)d_in[0];
    const float *ew[4], *eb[4], *dw[4], *db[4];
    for (int i = 0; i < 4; ++i) { ew[i] = (const float*)d_in[1 + 2 * i]; eb[i] = (const float*)d_in[2 + 2 * i]; }
    const float* cbs = (const float*)d_in[9];
    for (int i = 0; i < 4; ++i) { dw[i] = (const float*)d_in[10 + 2 * i]; db[i] = (const float*)d_in[11 + 2 * i]; }

    // ---- workspace layout (<= 136.7 MB) ----
    char* ws = (char*)d_ws;
    float*  A        = (float*)ws;                                   // [0,64MB)
    float*  Bb       = (float*)(ws + (size_t)64 * 1024 * 1024);      // [64,128MB)
    float*  tileMin  = (float*)(ws + (size_t)128 * 1024 * 1024);     // 8MB (VQ phase)
    float*  reconF   = (float*)(ws + (size_t)128 * 1024 * 1024);     // 2MB overlay (post-VQ)
    unsigned short* codes_ws = (unsigned short*)(ws + (size_t)136 * 1024 * 1024);  // 512KB
    float*  cnormF   = (float*)(ws + (size_t)136 * 1024 * 1024 + 524288);          // 32KB
    float*  Zrow     = (float*)(ws + (size_t)136 * 1024 * 1024 + 524288 + 32768);  // 128KB
    float*  lossp    = (float*)(ws + (size_t)136 * 1024 * 1024 + 524288 + 32768 + 131072);

    rf_prep<<<NCB * CBS, 64, 0, stream>>>(cbs, cnormF, lossp);

    // encoder: audio -> A -> Bb -> A -> Bb(=z_col)
    rf_enc<1,   64,  65536><<<dim3(64, 8,  NB), 256, 0, stream>>>(audio, ew[0], eb[0], A);
    rf_enc<64,  128, 32768><<<dim3(32, 16, NB), 256, 0, stream>>>(A,  ew[1], eb[1], Bb);
    rf_enc<128, 256, 16384><<<dim3(16, 32, NB), 256, 0, stream>>>(Bb, ew[2], eb[2], A);
    rf_enc<256, 512, 8192 ><<<dim3(8,  64, NB), 256, 0, stream>>>(A,  ew[3], eb[3], Bb);

    // z_col(Bb) -> R_row(A)  [32768][512]
    rf_tr<512, 4096><<<dim3(128, 16, NB), 256, 0, stream>>>(Bb, A);

    // residual VQ (row-major): R = A, Q = Bb
    for (int i = 0; i < NCB; ++i) {
        const float* cbi = cbs + (size_t)i * CBS * HID;
        const float* cni = cnormF + (size_t)i * CBS;
        rf_z   <<<512, 256, 0, stream>>>(A, Zrow);
        rf_pref<<<dim3(512, 8), 256, 0, stream>>>(cbi, cni, A, tileMin);
        rf_fin <<<2048, 256, 0, stream>>>(cbi, cni, A, Zrow, tileMin,
                                          codes_ws + (size_t)i * 32768);
        rf_comb<<<512, 256, 0, stream>>>(cbi, codes_ws + (size_t)i * 32768,
                                         A, Bb, lossp, i);
    }

    // Q_row(Bb) -> Q_col(A)
    rf_tr<4096, 512><<<dim3(16, 128, NB), 256, 0, stream>>>(Bb, A);

    // decoder (f32): A -> Bb -> A -> Bb -> reconF
    rf_dec<512, 256, 4096,  8, 0><<<dim3(16,  32, NB), 256, 0, stream>>>(A,  dw[0], db[0], Bb);
    rf_dec<256, 128, 8192,  8, 0><<<dim3(32,  16, NB), 256, 0, stream>>>(Bb, dw[1], db[1], A);
    rf_dec<128, 64,  16384, 8, 0><<<dim3(64,  8,  NB), 256, 0, stream>>>(A,  dw[2], db[2], Bb);
    rf_dec<64,  1,   32768, 1, 1><<<dim3(128, 1,  NB), 256, 0, stream>>>(Bb, dw[3], db[3], reconF);

    // single writer of d_out, last dispatch
    rf_emit<<<3073, 256, 0, stream>>>(reconF, codes_ws, lossp, out);
}

// Round 16
// 14983.905 us; speedup vs baseline: 1.2989x; 1.2989x over previous
//
#include <hip/hip_runtime.h>
#include <hip/hip_bf16.h>
#include <math.h>

#define NCB 8
#define CBS 1024
#define HID 512
#define NB 8
#define TLAT 4096
#define DELTA 6.0e-5f

__global__ void rg_sentinel(float* out, float v)
{
    out[threadIdx.x] = v;
}

// ---------------- encoder conv (verbatim r15): f64 interior, co-block 8 ----------------
template<int CIN, int COUT, int LIN>
__global__ __launch_bounds__(256)
void rg_enc(const float* __restrict__ x, const float* __restrict__ w,
            const float* __restrict__ bias, float* __restrict__ y)
{
    constexpr int LOUT = LIN / 2;
    __shared__ float xs[2][520];
    const int tid = threadIdx.x;
    const int t0  = blockIdx.x * 512;
    const int co0 = blockIdx.y * 8;
    const int b   = blockIdx.z;
    const float* xb = x + (size_t)b * CIN * LIN;
    const int base = 2 * t0 - 8;

    double acc[8][2];
#pragma unroll
    for (int c = 0; c < 8; ++c) acc[c][0] = acc[c][1] = (double)bias[co0 + c];

    for (int ci = 0; ci < CIN; ++ci) {
        const float* xc = xb + (size_t)ci * LIN;
        __syncthreads();
        for (int idx = tid; idx < 1040; idx += 256) {
            const int xi = base + idx;
            xs[idx & 1][idx >> 1] = ((unsigned)xi < (unsigned)LIN) ? xc[xi] : 0.f;
        }
        __syncthreads();
        const float* wc = w + ((size_t)co0 * CIN + ci) * 15;
#pragma unroll
        for (int k = 0; k < 15; ++k) {
            const int p  = (k + 1) & 1;
            const int jb = (k + 1) >> 1;
            const double x0 = (double)xs[p][tid + jb];
            const double x1 = (double)xs[p][tid + 256 + jb];
#pragma unroll
            for (int c = 0; c < 8; ++c) {
                const double wv = (double)wc[c * CIN * 15 + k];
                acc[c][0] = fma(wv, x0, acc[c][0]);
                acc[c][1] = fma(wv, x1, acc[c][1]);
            }
        }
    }
#pragma unroll
    for (int c = 0; c < 8; ++c) {
        float* yp = y + ((size_t)b * COUT + co0 + c) * LOUT;
        const double a0 = acc[c][0], a1 = acc[c][1];
        yp[t0 + tid]       = (float)(a0 > 0.0 ? a0 : expm1(a0));
        yp[t0 + tid + 256] = (float)(a1 > 0.0 ? a1 : expm1(a1));
    }
}

// ---------------- tiled transpose (verbatim r15) ----------------
template<int RIN, int CIN_>
__global__ __launch_bounds__(256)
void rg_tr(const float* __restrict__ in, float* __restrict__ out)
{
    __shared__ float tile[32][33];
    const int c0 = blockIdx.x * 32, r0 = blockIdx.y * 32, b = blockIdx.z;
    const int lx = threadIdx.x & 31, ly = threadIdx.x >> 5;
    const float* ib = in + (size_t)b * RIN * CIN_;
    float* ob = out + (size_t)b * RIN * CIN_;
#pragma unroll
    for (int m = 0; m < 4; ++m)
        tile[ly + m * 8][lx] = ib[(size_t)(r0 + ly + m * 8) * CIN_ + c0 + lx];
    __syncthreads();
#pragma unroll
    for (int m = 0; m < 4; ++m)
        ob[(size_t)(c0 + ly + m * 8) * RIN + r0 + lx] = tile[lx][ly + m * 8];
}

// ---------------- NEW decoder convT (layers 1-3): LDS x-tile, 8u x 2co per thread --------
// block: 256 u-positions x 16 co; LDS x chunk diag-swizzled (p = j + (j>>3)) -> conflict-free.
// Numerically unconstrained (recon threshold 20.48).
template<int CIN, int COUT, int LIN>
__global__ __launch_bounds__(256)
void rg_dec(const float* __restrict__ x, const float* __restrict__ w,
            const float* __restrict__ bias, float* __restrict__ y)
{
    constexpr int LOUT = LIN * 2;
    constexpr int CIC = 16;
    __shared__ float xs[CIC][304];               // j in [0,263] -> p = j+(j>>3) <= 295
    const int tid = threadIdx.x;
    const int ug  = tid & 31;                    // u-group: uBase = u0 + ug*8
    const int cg  = tid >> 5;                    // co-pair: co = co0 + cg*2
    const int u0  = blockIdx.x * 256;
    const int co0 = blockIdx.y * 16;
    const int b   = blockIdx.z;
    const int co  = co0 + cg * 2;
    const float* xb = x + (size_t)b * CIN * LIN;

    float acc[2][16];                            // [co][2*uu+s] = y[co][2*(uBase+uu)+s]
#pragma unroll
    for (int c = 0; c < 2; ++c) {
        const float bv = bias[co + c];
#pragma unroll
        for (int k = 0; k < 16; ++k) acc[c][k] = bv;
    }

    for (int cc = 0; cc < CIN; cc += CIC) {
        __syncthreads();
#pragma unroll
        for (int ci2 = 0; ci2 < CIC; ++ci2) {
            const float* xc = xb + (size_t)(cc + ci2) * LIN;
            for (int j = tid; j < 264; j += 256) {
                const int xj = u0 - 3 + j;
                xs[ci2][j + (j >> 3)] = ((unsigned)xj < (unsigned)LIN) ? xc[xj] : 0.f;
            }
        }
        __syncthreads();

#pragma unroll 4
        for (int ci = 0; ci < CIC; ++ci) {
            float xv[15];
#pragma unroll
            for (int m = 0; m < 15; ++m) {
                const int j = ug * 8 + m;
                xv[m] = xs[ci][j + (j >> 3)];
            }
            const float* wc = w + ((size_t)(cc + ci) * COUT + co) * 15;
            float wr[2][15];
#pragma unroll
            for (int c = 0; c < 2; ++c)
#pragma unroll
                for (int k = 0; k < 15; ++k) wr[c][k] = wc[c * 15 + k];

#pragma unroll
            for (int c = 0; c < 2; ++c) {
#pragma unroll
                for (int dj = 0; dj < 8; ++dj) {
                    const float wo = wr[c][14 - 2 * dj];
#pragma unroll
                    for (int uu = 0; uu < 8; ++uu)
                        acc[c][2 * uu + 1] = fmaf(xv[uu + dj], wo, acc[c][2 * uu + 1]);
                    if (dj < 7) {
                        const float we = wr[c][13 - 2 * dj];
#pragma unroll
                        for (int uu = 0; uu < 8; ++uu)
                            acc[c][2 * uu] = fmaf(xv[uu + dj], we, acc[c][2 * uu]);
                    }
                }
            }
        }
    }

#pragma unroll
    for (int c = 0; c < 2; ++c) {
        float* yp = y + ((size_t)b * COUT + co + c) * LOUT + 2 * (size_t)(u0 + ug * 8);
#pragma unroll
        for (int q = 0; q < 4; ++q) {
            float4 o;
            o.x = acc[c][q * 4 + 0]; o.y = acc[c][q * 4 + 1];
            o.z = acc[c][q * 4 + 2]; o.w = acc[c][q * 4 + 3];
            float* ov = (float*)&o;
#pragma unroll
            for (int e = 0; e < 4; ++e) ov[e] = ov[e] > 0.f ? ov[e] : expm1f(ov[e]);
            *(float4*)(yp + q * 4) = o;
        }
    }
}

// ---------------- final decoder layer (64->1, tanh) — verbatim r15 style ----------------
__global__ __launch_bounds__(256)
void rg_dec4(const float* __restrict__ x, const float* __restrict__ w,
             const float* __restrict__ bias, float* __restrict__ y)
{
    constexpr int CIN = 64, LIN = 32768, LOUT = 65536;
    const int u = blockIdx.x * 256 + threadIdx.x;
    const int b = blockIdx.z;
    float a0 = bias[0], a1 = bias[0];
    const float* xb = x + (size_t)b * CIN * LIN;
    for (int ci = 0; ci < CIN; ++ci) {
        const float* xc = xb + (size_t)ci * LIN;
        const float* wc = w + (size_t)ci * 15;
#pragma unroll
        for (int dj = 0; dj < 8; ++dj) {
            const int j = u - 3 + dj;
            const float xv = ((unsigned)j < (unsigned)LIN) ? xc[j] : 0.f;
            if (dj < 7) a0 = fmaf(xv, wc[13 - 2 * dj], a0);
            a1 = fmaf(xv, wc[14 - 2 * dj], a1);
        }
    }
    float* yp = y + (size_t)b * LOUT + 2 * (size_t)u;
    yp[0] = tanhf(a0);
    yp[1] = tanhf(a1);
}

// ---------------- prep (verbatim r15) ----------------
__global__ __launch_bounds__(64)
void rg_prep(const float* __restrict__ cb, float* __restrict__ cnormF,
             float* __restrict__ lossp)
{
    __shared__ double red[64];
    const int rrow = blockIdx.x;
    const float* src = cb + (size_t)rrow * HID;
    const int lane = threadIdx.x;
    double s = 0.0;
#pragma unroll
    for (int m = 0; m < 8; ++m) {
        const float v = src[lane * 8 + m];
        s += (double)__fmul_rn(v, v);
    }
    red[lane] = s;
    __syncthreads();
    if (lane == 0) {
        double tot = 0.0;
        for (int i = 0; i < 64; ++i) tot += red[i];
        cnormF[rrow] = (float)tot;
        if (rrow == 0) lossp[0] = 0.f;
    }
}

// ---------------- Z pre-pass (verbatim r15) ----------------
__global__ __launch_bounds__(256)
void rg_z(const float* __restrict__ R, float* __restrict__ Zrow)
{
    __shared__ double zp[64][4];
    const int tid = threadIdx.x;
    const int gr0 = blockIdx.x * 64;
    const int row = tid & 63, p = tid >> 6;
    const float* Rr = R + (size_t)(gr0 + row) * HID + p * 128;
    double s = 0.0;
    for (int i = 0; i < 128; ++i) {
        const float v = Rr[i];
        s += (double)__fmul_rn(v, v);
    }
    zp[row][p] = s;
    __syncthreads();
    if (tid < 64)
        Zrow[gr0 + tid] = (float)(((zp[tid][0] + zp[tid][1]) + zp[tid][2]) + zp[tid][3]);
}

// ---------------- f32 prefilter (verbatim r15) ----------------
__global__ __launch_bounds__(256)
void rg_pref(const float* __restrict__ cb, const float* __restrict__ cnormF,
             const float* __restrict__ R, float* __restrict__ tileMin)
{
    __shared__ __align__(16) float Rt[32][64];
    __shared__ __align__(16) float Ct[32][128];
    const int tid = threadIdx.x;
    const int gr0 = blockIdx.x * 64;
    const int cb0 = blockIdx.y * 128;
    const float* Rbase = R + (size_t)gr0 * HID;
    const int ir = tid >> 4, jc = tid & 15;

    float acc[4][8];
#pragma unroll
    for (int r = 0; r < 4; ++r)
#pragma unroll
        for (int c = 0; c < 8; ++c) acc[r][c] = 0.f;

    for (int kc = 0; kc < 16; ++kc) {
        const int k0 = kc * 32;
        __syncthreads();
#pragma unroll
        for (int rep = 0; rep < 2; ++rep) {
            const int row  = (tid >> 3) + 32 * rep;
            const int koff = (tid & 7) * 4;
            const float4 v = *(const float4*)(Rbase + (size_t)row * HID + k0 + koff);
            Rt[koff + 0][row] = v.x; Rt[koff + 1][row] = v.y;
            Rt[koff + 2][row] = v.z; Rt[koff + 3][row] = v.w;
        }
        {
            const int cc = tid >> 1, h = (tid & 1) * 16;
            const float* s = cb + (size_t)(cb0 + cc) * HID + k0 + h;
            const float4 v0 = *(const float4*)s;
            const float4 v1 = *(const float4*)(s + 4);
            const float4 v2 = *(const float4*)(s + 8);
            const float4 v3 = *(const float4*)(s + 12);
            Ct[h + 0][cc] = v0.x; Ct[h + 1][cc] = v0.y; Ct[h + 2][cc] = v0.z; Ct[h + 3][cc] = v0.w;
            Ct[h + 4][cc] = v1.x; Ct[h + 5][cc] = v1.y; Ct[h + 6][cc] = v1.z; Ct[h + 7][cc] = v1.w;
            Ct[h + 8][cc] = v2.x; Ct[h + 9][cc] = v2.y; Ct[h +10][cc] = v2.z; Ct[h +11][cc] = v2.w;
            Ct[h +12][cc] = v3.x; Ct[h +13][cc] = v3.y; Ct[h +14][cc] = v3.z; Ct[h +15][cc] = v3.w;
        }
        __syncthreads();

#pragma unroll
        for (int kk = 0; kk < 32; ++kk) {
            const float4 rv = *(const float4*)&Rt[kk][ir * 4];
            const float4 c0v = *(const float4*)&Ct[kk][jc * 8];
            const float4 c1v = *(const float4*)&Ct[kk][jc * 8 + 4];
            const float rr[4] = {rv.x, rv.y, rv.z, rv.w};
            const float cc8[8] = {c0v.x, c0v.y, c0v.z, c0v.w, c1v.x, c1v.y, c1v.z, c1v.w};
#pragma unroll
            for (int r = 0; r < 4; ++r)
#pragma unroll
                for (int c = 0; c < 8; ++c)
                    acc[r][c] = fmaf(rr[r], cc8[c], acc[r][c]);
        }
    }

#pragma unroll
    for (int r = 0; r < 4; ++r) {
        float m = 3.0e38f;
#pragma unroll
        for (int c = 0; c < 8; ++c) {
            const int ci = cb0 + jc * 8 + c;
            const float s = fmaf(-2.f, acc[r][c], cnormF[ci]);
            m = fminf(m, s);
        }
        const float o = __shfl_xor(m, 1, 64);
        m = fminf(m, o);
        if ((jc & 1) == 0)
            tileMin[(size_t)(gr0 + ir * 4 + r) * 64 + (cb0 >> 4) + (jc >> 1)] = m;
    }
}

// ---------------- exact rescore — wave-parallel (verbatim r15) ----------------
__global__ __launch_bounds__(256)
void rg_fin(const float* __restrict__ cb, const float* __restrict__ cnormF,
            const float* __restrict__ R, const float* __restrict__ Zrow,
            const float* __restrict__ tileMin, unsigned short* __restrict__ codesOut)
{
    __shared__ float tmS[16][64];
    __shared__ unsigned char tlistS[16][16];
    __shared__ int tcntS[16];

    const int tid = threadIdx.x;
    const int gr0 = blockIdx.x * 16;

    for (int e = tid; e < 16 * 64; e += 256)
        tmS[e >> 6][e & 63] = tileMin[(size_t)(gr0 + (e >> 6)) * 64 + (e & 63)];
    __syncthreads();
    if (tid < 16) {
        float m = 3.0e38f;
        for (int t = 0; t < 64; ++t) m = fminf(m, tmS[tid][t]);
        int cnt = 0;
        const float thr_ = m + DELTA;
        for (int t = 0; t < 64; ++t)
            if (tmS[tid][t] <= thr_) { if (cnt < 16) tlistS[tid][cnt] = (unsigned char)t; ++cnt; }
        tcntS[tid] = (cnt > 16) ? 64 : cnt;
    }
    __syncthreads();

    const int wave = tid >> 6;
    const int lane = tid & 63;
    const int rloc = wave * 4 + (lane >> 4);
    const int cg   = lane & 15;
    const int grow = gr0 + rloc;
    const float* Rr = R + (size_t)grow * HID;
    const float Zr = Zrow[grow];
    const int myCnt = tcntS[rloc];

    int maxc = myCnt;
    maxc = max(maxc, __shfl_xor(maxc, 16, 64));
    maxc = max(maxc, __shfl_xor(maxc, 32, 64));

    float bestS = 3.0e38f; int bestC = 0x7fffffff;
    for (int li = 0; li < maxc; ++li) {
        if (li < myCnt) {
            const int tt = (myCnt <= 16) ? (int)tlistS[rloc][li] : li;
            const int ci = tt * 16 + cg;
            const float* cp = cb + (size_t)ci * HID;
            double a = 0.0;
            for (int d = 0; d < 512; ++d)
                a = fma((double)Rr[d], (double)cp[d], a);
            const float M32 = (float)a;
            const float s = __fadd_rn(__fsub_rn(Zr, __fadd_rn(M32, M32)), cnormF[ci]);
            if (s < bestS || (s == bestS && ci < bestC)) { bestS = s; bestC = ci; }
        }
    }
#pragma unroll
    for (int off = 8; off; off >>= 1) {
        const float ov = __shfl_xor(bestS, off, 16);
        const int   oc = __shfl_xor(bestC, off, 16);
        if (ov < bestS || (ov == bestS && oc < bestC)) { bestS = ov; bestC = oc; }
    }
    if (cg == 0) codesOut[grow] = (unsigned short)bestC;
}

// ---------------- ST update + loss (verbatim r15) ----------------
__global__ __launch_bounds__(256)
void rg_comb(const float* __restrict__ cb, const unsigned short* __restrict__ codesIn,
             float* __restrict__ R, float* __restrict__ Q,
             float* __restrict__ loss_acc, int stage)
{
    __shared__ int codes_l[64];
    const int tid = threadIdx.x;
    const int gr0 = blockIdx.x * 64;
    float* Rb = R + (size_t)gr0 * HID;
    float* Qb = Q + (size_t)gr0 * HID;

    if (tid < 64) codes_l[tid] = (int)codesIn[gr0 + tid];
    __syncthreads();

    float ls = 0.f;
    for (int e = tid; e < 64 * HID; e += 256) {
        const int row = e >> 9;
        const int c = codes_l[row];
        const float rr = Rb[e];
        const float q = cb[(size_t)c * HID + (e & 511)];
        const float diff  = __fsub_rn(q, rr);
        const float zqst  = __fadd_rn(rr, diff);
        ls = fmaf(diff, diff, ls);
        Rb[e] = __fsub_rn(rr, zqst);
        if (stage == 0) Qb[e] = zqst; else Qb[e] = __fadd_rn(Qb[e], zqst);
    }
#pragma unroll
    for (int off = 32; off; off >>= 1) ls += __shfl_down(ls, off, 64);
    if ((tid & 63) == 0) atomicAdd(loss_acc, ls);
}

// ---------------- single writer of d_out (verbatim r15) ----------------
__global__ __launch_bounds__(256)
void rg_emit(const float* __restrict__ reconF, const unsigned short* __restrict__ codes_ws,
             const float* __restrict__ loss_acc, float* __restrict__ out)
{
    const int j = blockIdx.x * 256 + threadIdx.x;
    if (j >= 524288 + 1 + NCB * 32768) return;
    if (j < 524288)       out[j] = reconF[j];
    else if (j == 524288) out[j] = loss_acc[0] * 1.25f * (1.0f / 16777216.0f);
    else                  out[j] = (float)codes_ws[j - 524289];
}

extern "C" void kernel_launch(void* const* d_in, const int* in_sizes, int n_in,
                              void* d_out, int out_size, void* d_ws, size_t ws_size,
                              hipStream_t stream)
{
    float* out = (float*)d_out;

    if (n_in != 18)                                   { rg_sentinel<<<1, 256, 0, stream>>>(out, 1111.0f); return; }
    if (in_sizes[0] != 8 * 65536 || in_sizes[9] != NCB * CBS * HID ||
        in_sizes[1] != 64 * 15 || in_sizes[10] != 512 * 256 * 15)
                                                      { rg_sentinel<<<1, 256, 0, stream>>>(out, 3333.0f); return; }
    if (out_size != 524288 + 1 + NCB * 32768)         { rg_sentinel<<<1, 256, 0, stream>>>(out, 5555.0f); return; }
    if (ws_size < (size_t)137 * 1024 * 1024)          { rg_sentinel<<<1, 256, 0, stream>>>(out, 7777.0f); return; }

    const float* audio = (const float*)d_in[0];
    const float *ew[4], *eb[4], *dw[4], *db[4];
    for (int i = 0; i < 4; ++i) { ew[i] = (const float*)d_in[1 + 2 * i]; eb[i] = (const float*)d_in[2 + 2 * i]; }
    const float* cbs = (const float*)d_in[9];
    for (int i = 0; i < 4; ++i) { dw[i] = (const float*)d_in[10 + 2 * i]; db[i] = (const float*)d_in[11 + 2 * i]; }

    // ---- workspace layout (<= 136.7 MB) ----
    char* ws = (char*)d_ws;
    float*  A        = (float*)ws;                                   // [0,64MB)
    float*  Bb       = (float*)(ws + (size_t)64 * 1024 * 1024);      // [64,128MB)
    float*  tileMin  = (float*)(ws + (size_t)128 * 1024 * 1024);     // 8MB (VQ phase)
    float*  reconF   = (float*)(ws + (size_t)128 * 1024 * 1024);     // 2MB overlay (post-VQ)
    unsigned short* codes_ws = (unsigned short*)(ws + (size_t)136 * 1024 * 1024);  // 512KB
    float*  cnormF   = (float*)(ws + (size_t)136 * 1024 * 1024 + 524288);          // 32KB
    float*  Zrow     = (float*)(ws + (size_t)136 * 1024 * 1024 + 524288 + 32768);  // 128KB
    float*  lossp    = (float*)(ws + (size_t)136 * 1024 * 1024 + 524288 + 32768 + 131072);

    rg_prep<<<NCB * CBS, 64, 0, stream>>>(cbs, cnormF, lossp);

    // encoder: audio -> A -> Bb -> A -> Bb(=z_col)
    rg_enc<1,   64,  65536><<<dim3(64, 8,  NB), 256, 0, stream>>>(audio, ew[0], eb[0], A);
    rg_enc<64,  128, 32768><<<dim3(32, 16, NB), 256, 0, stream>>>(A,  ew[1], eb[1], Bb);
    rg_enc<128, 256, 16384><<<dim3(16, 32, NB), 256, 0, stream>>>(Bb, ew[2], eb[2], A);
    rg_enc<256, 512, 8192 ><<<dim3(8,  64, NB), 256, 0, stream>>>(A,  ew[3], eb[3], Bb);

    // z_col(Bb) -> R_row(A)  [32768][512]
    rg_tr<512, 4096><<<dim3(128, 16, NB), 256, 0, stream>>>(Bb, A);

    // residual VQ (row-major): R = A, Q = Bb
    for (int i = 0; i < NCB; ++i) {
        const float* cbi = cbs + (size_t)i * CBS * HID;
        const float* cni = cnormF + (size_t)i * CBS;
        rg_z   <<<512, 256, 0, stream>>>(A, Zrow);
        rg_pref<<<dim3(512, 8), 256, 0, stream>>>(cbi, cni, A, tileMin);
        rg_fin <<<2048, 256, 0, stream>>>(cbi, cni, A, Zrow, tileMin,
                                          codes_ws + (size_t)i * 32768);
        rg_comb<<<512, 256, 0, stream>>>(cbi, codes_ws + (size_t)i * 32768,
                                         A, Bb, lossp, i);
    }

    // Q_row(Bb) -> Q_col(A)
    rg_tr<4096, 512><<<dim3(16, 128, NB), 256, 0, stream>>>(Bb, A);

    // decoder: A -> Bb -> A -> Bb -> reconF
    rg_dec<512, 256, 4096 ><<<dim3(16, 16, NB), 256, 0, stream>>>(A,  dw[0], db[0], Bb);
    rg_dec<256, 128, 8192 ><<<dim3(32, 8,  NB), 256, 0, stream>>>(Bb, dw[1], db[1], A);
    rg_dec<128, 64,  16384><<<dim3(64, 4,  NB), 256, 0, stream>>>(A,  dw[2], db[2], Bb);
    rg_dec4<<<dim3(128, 1, NB), 256, 0, stream>>>(Bb, dw[3], db[3], reconF);

    // single writer of d_out, last dispatch
    rg_emit<<<3073, 256, 0, stream>>>(reconF, codes_ws, lossp, out);
}